// Round 10
// baseline (286.413 us; speedup 1.0000x reference)
//
#include <hip/hip_runtime.h>
#include <math.h>
#include <type_traits>

#define BB 2
#define SS 2048
#define DD 64
#define HH 12
// Q pre-scaled by 1/ln2 in qkv; exp(s-16) == exp2(s' - 16/ln2)
#define C2FIX 23.083120654223414f

typedef _Float16 v8h __attribute__((ext_vector_type(8)));
typedef short    v8s __attribute__((ext_vector_type(8)));
typedef short    v4s __attribute__((ext_vector_type(4)));
typedef float    v4f __attribute__((ext_vector_type(4)));
typedef unsigned int v2u __attribute__((ext_vector_type(2)));

__device__ __forceinline__ unsigned short f2bf(float f) {
    unsigned u = __float_as_uint(f);
    u += 0x7FFF + ((u >> 16) & 1);          // RTN-even
    return (unsigned short)(u >> 16);
}

// ---------------------------------------------------------------------------
// Kernel 0: prep. x -> x16 fp16; [Wq|Wk|Wv] -> W16 fp16 B-layout [2304][64];
// Wo -> WoT fp16 [64][768].  (exact R15 baseline)
// ---------------------------------------------------------------------------
__global__ __launch_bounds__(256) void prep_kernel(
    const float* __restrict__ x,
    const float* __restrict__ Wq, const float* __restrict__ Wk,
    const float* __restrict__ Wv, const float* __restrict__ Wo,
    _Float16* __restrict__ x16, _Float16* __restrict__ W16,
    _Float16* __restrict__ WoT)
{
    const int idx = blockIdx.x * 256 + threadIdx.x;
    if (idx < 262144) {
        x16[idx] = (_Float16)x[idx];
    } else if (idx < 262144 + 147456) {
        const int t = idx - 262144;
        const int k = t / 2304, c = t % 2304;        // coalesced read over c
        const int mat = c / 768, cc = c % 768;
        const float* W = (mat == 0) ? Wq : (mat == 1) ? Wk : Wv;
        W16[c * 64 + k] = (_Float16)W[k * 768 + cc];
    } else {
        const int e = idx - 262144 - 147456;         // < 49152
        WoT[(e & 63) * 768 + (e >> 6)] = (_Float16)Wo[e];
    }
}

// ---------------------------------------------------------------------------
// Kernel 1: QKV projection via MFMA (R15 baseline). R22: V^T store is now
// TILE-BLOCKED: VT2[bh][tile=s>>6][d][key=s&63] — each 64-key tile's V^T
// is a contiguous 8 KB block (L1-resident in attn). In-tile key =
// 16*wave+4*quad+r, r contiguous -> same packed 8-B store as before.
// ---------------------------------------------------------------------------
__global__ __launch_bounds__(256) void qkv_kernel(
    const _Float16* __restrict__ x16, const _Float16* __restrict__ W16,
    const float* __restrict__ bq, const float* __restrict__ bk,
    const float* __restrict__ bv,
    _Float16* __restrict__ Q16, _Float16* __restrict__ K16,
    unsigned short* __restrict__ VT)
{
    const int r0  = blockIdx.x * 64;
    const int c0g = blockIdx.y * 64;
    const int mat = c0g / 768, cc0 = c0g % 768;
    const int h   = cc0 >> 6;
    const int b   = r0 >> 11, s0 = r0 & 2047;

    const int wave = threadIdx.x >> 6, lane = threadIdx.x & 63;
    const int llow = lane & 15, quad = lane >> 4;
    const int rowbase = r0 + 16 * wave;

    const float* bias = (mat == 0) ? bq : (mat == 1) ? bk : bv;

    v8h a0 = *(const v8h*)(x16 + (size_t)(rowbase + llow) * 64 + quad * 8);
    v8h a1 = *(const v8h*)(x16 + (size_t)(rowbase + llow) * 64 + 32 + quad * 8);

    v4f acc[4];
    float bv4[4];
#pragma unroll
    for (int nb = 0; nb < 4; nb++) {
        const int col = c0g + 16 * nb + llow;
        v8h b0 = *(const v8h*)(W16 + (size_t)col * 64 + quad * 8);
        v8h b1 = *(const v8h*)(W16 + (size_t)col * 64 + 32 + quad * 8);
        v4f a = (v4f){0.f, 0.f, 0.f, 0.f};
        a = __builtin_amdgcn_mfma_f32_16x16x32_f16(a0, b0, a, 0, 0, 0);
        a = __builtin_amdgcn_mfma_f32_16x16x32_f16(a1, b1, a, 0, 0, 0);
        acc[nb] = a;
        bv4[nb] = bias[cc0 + 16 * nb + llow];
    }

    const int bh = b * HH + h;
    if (mat == 0) {                                  // Q: pre-scale by 1/ln2
#pragma unroll
        for (int nb = 0; nb < 4; nb++)
#pragma unroll
            for (int r = 0; r < 4; r++) {
                const int s = s0 + 16 * wave + quad * 4 + r;
                Q16[((size_t)bh * SS + s) * 64 + 16 * nb + llow] =
                    (_Float16)((acc[nb][r] + bv4[nb]) * 1.4426950408889634f);
            }
    } else if (mat == 1) {
#pragma unroll
        for (int nb = 0; nb < 4; nb++)
#pragma unroll
            for (int r = 0; r < 4; r++) {
                const int s = s0 + 16 * wave + quad * 4 + r;
                K16[((size_t)bh * SS + s) * 64 + 16 * nb + llow] =
                    (_Float16)(acc[nb][r] + bv4[nb]);
            }
    } else {                                         // V^T bf16, tile-blocked
        const int tile = s0 >> 6;                    // block-uniform
        const int kin  = 16 * wave + quad * 4;       // in-tile key, 4 consecutive
#pragma unroll
        for (int nb = 0; nb < 4; nb++) {
            const int d = 16 * nb + llow;
            unsigned short p0 = f2bf(acc[nb][0] + bv4[nb]);
            unsigned short p1 = f2bf(acc[nb][1] + bv4[nb]);
            unsigned short p2 = f2bf(acc[nb][2] + bv4[nb]);
            unsigned short p3 = f2bf(acc[nb][3] + bv4[nb]);
            v2u pk = (v2u){(unsigned)p0 | ((unsigned)p1 << 16),
                           (unsigned)p2 | ((unsigned)p3 << 16)};
            *(v2u*)&VT[(((size_t)bh * 32 + tile) * 64 + d) * 64 + kin] = pk;
        }
    }
}

// ---------------------------------------------------------------------------
// Kernel 2: MFMA flash attention, R22: ZERO LDS, ZERO BARRIERS. Evidence
// (R15≈R19≈R20≈R21 all ~43-45us despite structurally different rounds;
// all pipes <30%): attn is phase-lockstep-bound — co-resident blocks hit
// barriers in phase, so serial QKT->exp2->PV chains never overlap across
// blocks. Fix: waves fully independent. Each wave loads K (K16 rows =
// 16x64B full cache lines) and V (VT2 8-KB L1-resident tiles) DIRECTLY
// into registers, software-pipelined one tile ahead (A/B fragment sets,
// compiler-managed waitcnts). This fixes both R16 failure causes: no
// prefetch (now 1 tile ≈ 1500cy ahead) and 4096-B-strided V rows (now
// tile-blocked). P stays in registers (R20 K=16-PV layout identity);
// ls via MFMA ones-trick. ~200 VGPR -> 2 waves/SIMD, 8 independent
// chains/CU.
// ---------------------------------------------------------------------------
struct Frags {
    v8h k[8];     // K A-frags: [cb*2+half]
    v4s v[16];    // V^T B-frags (K=16): [nb*4+cb]
};

__global__ __launch_bounds__(256, 2) void attn_kernel(
    const _Float16* __restrict__ Q16, const _Float16* __restrict__ K16,
    const unsigned short* __restrict__ VTg, _Float16* __restrict__ O16)
{
    const int bh    = blockIdx.y;
    const int qtile = (int)((blockIdx.x + 11 * blockIdx.y) & 31);   // balance swizzle
    const int wave  = threadIdx.x >> 6;
    const int lane  = threadIdx.x & 63;
    const int llow  = lane & 15;
    const int quad  = lane >> 4;
    const int q0    = qtile * 64 + 16 * wave;

    const _Float16*       Kp  = K16 + (size_t)bh * SS * 64;
    const unsigned short* Vp2 = VTg + (size_t)bh * 32 * 4096;

    const _Float16* Qp = Q16 + ((size_t)bh * SS + q0) * 64;
    v8h qa0 = *(const v8h*)(Qp + llow * 64 + quad * 8);
    v8h qa1 = *(const v8h*)(Qp + llow * 64 + 32 + quad * 8);

    v4f o[4];
    v4f ls = (v4f){0.f, 0.f, 0.f, 0.f};             // row sums via MFMA
    const short one_bf = (short)0x3F80;              // bf16 1.0
    const v4s vones = (v4s){one_bf, one_bf, one_bf, one_bf};
#pragma unroll
    for (int nb = 0; nb < 4; nb++) o[nb] = (v4f){0.f, 0.f, 0.f, 0.f};

    const int nt   = qtile + 1;     // 64-key tiles needed
    const int qrow = q0 + llow;

    Frags fA, fB;

    // load tile t's K/V fragments for this wave (global -> regs, no LDS)
    auto stageT = [&](Frags& f, int t) {
        const _Float16* kb = Kp + (size_t)t * 64 * 64;
#pragma unroll
        for (int cb = 0; cb < 4; cb++) {
            f.k[cb * 2 + 0] = *(const v8h*)(kb + (16 * cb + llow) * 64 + quad * 8);
            f.k[cb * 2 + 1] = *(const v8h*)(kb + (16 * cb + llow) * 64 + 32 + quad * 8);
        }
        const unsigned short* vb = Vp2 + (size_t)t * 4096;
#pragma unroll
        for (int nb = 0; nb < 4; nb++)
#pragma unroll
            for (int cb = 0; cb < 4; cb++)
                f.v[nb * 4 + cb] = *(const v4s*)(vb + (16 * nb + llow) * 64
                                                 + 16 * cb + 4 * quad);
    };

    auto computeT = [&](int t, Frags& f, auto masked_c) {
        constexpr bool MASKED = decltype(masked_c)::value;
        const int kt = t * 64;

        // ---- S^T = K·Q^T: 4 col-blocks of 16 keys ----
        v4f sc[4];
#pragma unroll
        for (int cb = 0; cb < 4; cb++) {
            v4f a2 = (v4f){0.f, 0.f, 0.f, 0.f};
            a2 = __builtin_amdgcn_mfma_f32_16x16x32_f16(f.k[cb * 2 + 0], qa0, a2, 0, 0, 0);
            a2 = __builtin_amdgcn_mfma_f32_16x16x32_f16(f.k[cb * 2 + 1], qa1, a2, 0, 0, 0);
            sc[cb] = a2;  // C: col=llow=q-row, row=quad*4+r=key offset
        }

        // ---- quirky mask + exp2; pack P pairs in-register (K=16 A-frags) ----
        v4s pA[4];
#pragma unroll
        for (int cb = 0; cb < 4; cb++) {
            const int kbase = kt + 16 * cb + quad * 4;
            unsigned dw[2];
#pragma unroll
            for (int h2 = 0; h2 < 2; h2++) {
                float pv2[2];
#pragma unroll
                for (int j2 = 0; j2 < 2; j2++) {
                    const int r = h2 * 2 + j2;
                    const float sv = sc[cb][r];
                    const float e  = __builtin_amdgcn_exp2f(sv - C2FIX);
                    float p;
                    if constexpr (MASKED)
                        p = (kbase + r <= qrow && sv != 0.f) ? e : 0.f;
                    else
                        p = (sv != 0.f) ? e : 0.f;   // tril-zero quirk only
                    pv2[j2] = p;
                }
                dw[h2] = __builtin_amdgcn_perm(__float_as_uint(pv2[1]),
                                               __float_as_uint(pv2[0]),
                                               0x07060302u);
            }
            v2u pk = (v2u){dw[0], dw[1]};
            pA[cb] = *(const v4s*)&pk;   // A[row=llow][k=4quad+j]
        }

        // ---- row sums on the MFMA pipe: ls += P · ones (K=16) ----
#pragma unroll
        for (int cb = 0; cb < 4; cb++)
            ls = __builtin_amdgcn_mfma_f32_16x16x16bf16_1k(pA[cb], vones, ls, 0, 0, 0);

        // ---- PV via K=16 MFMAs (V frags already in regs) ----
#pragma unroll
        for (int nb = 0; nb < 4; nb++)
#pragma unroll
            for (int cb = 0; cb < 4; cb++)
                o[nb] = __builtin_amdgcn_mfma_f32_16x16x16bf16_1k(
                            pA[cb], f.v[nb * 4 + cb], o[nb], 0, 0, 0);
    };

    // ---- software-pipelined main loop, one tile ahead, A/B named buffers ----
    stageT(fA, 0);
    int t = 0;
    while (t + 2 <= nt - 1) {            // t and t+1 both non-final
        stageT(fB, t + 1); computeT(t, fA, std::false_type{});
        stageT(fA, t + 2); computeT(t + 1, fB, std::false_type{});
        t += 2;
    }
    if (t == nt - 2) {                   // t non-final, t+1 final
        stageT(fB, t + 1);
        computeT(t, fA, std::false_type{});
        computeT(t + 1, fB, std::true_type{});
    } else {                             // t == nt-1: final tile in fA
        computeT(t, fA, std::true_type{});
    }

    // ---- epilogue: ls[r] IS the full row sum for row quad*4+r ----
    float ir[4];
#pragma unroll
    for (int r = 0; r < 4; r++)
        ir[r] = 1.0f / ls[r];
    _Float16* Op = O16 + ((size_t)bh * SS + q0) * 64;
#pragma unroll
    for (int nb = 0; nb < 4; nb++)
#pragma unroll
        for (int r = 0; r < 4; r++)
            Op[(quad * 4 + r) * 64 + 16 * nb + llow] = (_Float16)(o[nb][r] * ir[r]);
}

// ---------------------------------------------------------------------------
// Kernel 3: output projection via MFMA (unchanged).
// ---------------------------------------------------------------------------
__global__ __launch_bounds__(256) void out_kernel(
    const _Float16* __restrict__ O16, const _Float16* __restrict__ WoT,
    const float* __restrict__ bo, float* __restrict__ out)
{
    __shared__ __align__(16) float red[4][16][66];
    const int r0   = blockIdx.x * 16;
    const int wave = threadIdx.x >> 6, lane = threadIdx.x & 63;
    const int llow = lane & 15, quad = lane >> 4;
    const int b = r0 >> 11, s = r0 & 2047;

    v4f acc[4];
#pragma unroll
    for (int cb = 0; cb < 4; cb++) acc[cb] = (v4f){0.f, 0.f, 0.f, 0.f};

#pragma unroll
    for (int i = 0; i < 6; i++) {
        const int kb = wave * 6 + i;                // 0..23
        const int h = kb >> 1, dseg = (kb & 1) * 32;
        v8h af = *(const v8h*)(O16 + ((size_t)(b * HH + h) * SS + s + llow) * 64 + dseg + quad * 8);
#pragma unroll
        for (int cb = 0; cb < 4; cb++) {
            v8h bf = *(const v8h*)(WoT + (size_t)(16 * cb + llow) * 768 + kb * 32 + quad * 8);
            acc[cb] = __builtin_amdgcn_mfma_f32_16x16x32_f16(af, bf, acc[cb], 0, 0, 0);
        }
    }

#pragma unroll
    for (int cb = 0; cb < 4; cb++)
#pragma unroll
        for (int r = 0; r < 4; r++)
            red[wave][quad * 4 + r][16 * cb + llow] = acc[cb][r];
    __syncthreads();

    const int col = threadIdx.x & 63, rr = threadIdx.x >> 6;
    const float bias = bo[col];
    for (int i = rr; i < 16; i += 4) {
        float sum = red[0][i][col] + red[1][i][col] + red[2][i][col] + red[3][i][col] + bias;
        out[(size_t)(r0 + i) * 64 + col] = sum;
    }
}

// ---------------------------------------------------------------------------
extern "C" void kernel_launch(void* const* d_in, const int* in_sizes, int n_in,
                              void* d_out, int out_size, void* d_ws, size_t ws_size,
                              hipStream_t stream)
{
    const float* x  = (const float*)d_in[0];
    const float* Wq = (const float*)d_in[1];
    const float* bq = (const float*)d_in[2];
    const float* Wk = (const float*)d_in[3];
    const float* bk = (const float*)d_in[4];
    const float* Wv = (const float*)d_in[5];
    const float* bv = (const float*)d_in[6];
    const float* Wo = (const float*)d_in[7];
    const float* bo = (const float*)d_in[8];
    float* out = (float*)d_out;

    char* w = (char*)d_ws;
    const size_t MB = 1024 * 1024;
    _Float16*       x16 = (_Float16*)(w);                 // 512 KB
    _Float16*       W16 = (_Float16*)(w + 512 * 1024);    // 288 KB
    _Float16*       WoT = (_Float16*)(w + 832 * 1024);    // 96 KB
    _Float16*       Q16 = (_Float16*)(w + 1 * MB);        // 6 MB each
    _Float16*       K16 = (_Float16*)(w + 7 * MB);
    unsigned short* VT  = (unsigned short*)(w + 13 * MB);
    _Float16*       O16 = (_Float16*)(w + 19 * MB);

    prep_kernel<<<1792, 256, 0, stream>>>(x, Wq, Wk, Wv, Wo, x16, W16, WoT);
    qkv_kernel<<<dim3(64, 36), 256, 0, stream>>>(x16, W16, bq, bk, bv, Q16, K16, VT);
    attn_kernel<<<dim3(32, BB * HH), 256, 0, stream>>>(Q16, K16, VT, O16);
    out_kernel<<<(BB * SS) / 16, 256, 0, stream>>>(O16, WoT, bo, out);
}

// Round 11
// 231.847 us; speedup vs baseline: 1.2354x; 1.2354x over previous
//
#include <hip/hip_runtime.h>
#include <math.h>
#include <type_traits>

#define BB 2
#define SS 2048
#define DD 64
#define HH 12
// Q pre-scaled by 1/ln2 in qkv; exp(s-16) == exp2(s' - 16/ln2)
#define C2FIX 23.083120654223414f

typedef _Float16 v8h __attribute__((ext_vector_type(8)));
typedef short    v8s __attribute__((ext_vector_type(8)));
typedef short    v4s __attribute__((ext_vector_type(4)));
typedef float    v4f __attribute__((ext_vector_type(4)));
typedef unsigned int v2u __attribute__((ext_vector_type(2)));

__device__ __forceinline__ unsigned short f2bf(float f) {
    unsigned u = __float_as_uint(f);
    u += 0x7FFF + ((u >> 16) & 1);          // RTN-even
    return (unsigned short)(u >> 16);
}

__device__ __forceinline__ void async16(const void* g, void* l) {
    __builtin_amdgcn_global_load_lds(
        (const __attribute__((address_space(1))) unsigned int*)g,
        (__attribute__((address_space(3))) unsigned int*)l, 16, 0, 0);
}

// ---------------------------------------------------------------------------
// Kernel 0: prep. x -> x16 fp16; [Wq|Wk|Wv] -> W16 fp16 B-layout [2304][64];
// Wo -> WoT fp16 [64][768].  (exact R15 baseline)
// ---------------------------------------------------------------------------
__global__ __launch_bounds__(256) void prep_kernel(
    const float* __restrict__ x,
    const float* __restrict__ Wq, const float* __restrict__ Wk,
    const float* __restrict__ Wv, const float* __restrict__ Wo,
    _Float16* __restrict__ x16, _Float16* __restrict__ W16,
    _Float16* __restrict__ WoT)
{
    const int idx = blockIdx.x * 256 + threadIdx.x;
    if (idx < 262144) {
        x16[idx] = (_Float16)x[idx];
    } else if (idx < 262144 + 147456) {
        const int t = idx - 262144;
        const int k = t / 2304, c = t % 2304;        // coalesced read over c
        const int mat = c / 768, cc = c % 768;
        const float* W = (mat == 0) ? Wq : (mat == 1) ? Wk : Wv;
        W16[c * 64 + k] = (_Float16)W[k * 768 + cc];
    } else {
        const int e = idx - 262144 - 147456;         // < 49152
        WoT[(e & 63) * 768 + (e >> 6)] = (_Float16)Wo[e];
    }
}

// ---------------------------------------------------------------------------
// Kernel 1: QKV projection via MFMA (R15 baseline). V^T stays TILE-BLOCKED
// (R22, verified): VT2[bh][tile=s>>6][d][key=s&63] — 8 KB contiguous per
// 64-key tile, L1-resident in attn. Same packed 8-B store.
// ---------------------------------------------------------------------------
__global__ __launch_bounds__(256) void qkv_kernel(
    const _Float16* __restrict__ x16, const _Float16* __restrict__ W16,
    const float* __restrict__ bq, const float* __restrict__ bk,
    const float* __restrict__ bv,
    _Float16* __restrict__ Q16, _Float16* __restrict__ K16,
    unsigned short* __restrict__ VT)
{
    const int r0  = blockIdx.x * 64;
    const int c0g = blockIdx.y * 64;
    const int mat = c0g / 768, cc0 = c0g % 768;
    const int h   = cc0 >> 6;
    const int b   = r0 >> 11, s0 = r0 & 2047;

    const int wave = threadIdx.x >> 6, lane = threadIdx.x & 63;
    const int llow = lane & 15, quad = lane >> 4;
    const int rowbase = r0 + 16 * wave;

    const float* bias = (mat == 0) ? bq : (mat == 1) ? bk : bv;

    v8h a0 = *(const v8h*)(x16 + (size_t)(rowbase + llow) * 64 + quad * 8);
    v8h a1 = *(const v8h*)(x16 + (size_t)(rowbase + llow) * 64 + 32 + quad * 8);

    v4f acc[4];
    float bv4[4];
#pragma unroll
    for (int nb = 0; nb < 4; nb++) {
        const int col = c0g + 16 * nb + llow;
        v8h b0 = *(const v8h*)(W16 + (size_t)col * 64 + quad * 8);
        v8h b1 = *(const v8h*)(W16 + (size_t)col * 64 + 32 + quad * 8);
        v4f a = (v4f){0.f, 0.f, 0.f, 0.f};
        a = __builtin_amdgcn_mfma_f32_16x16x32_f16(a0, b0, a, 0, 0, 0);
        a = __builtin_amdgcn_mfma_f32_16x16x32_f16(a1, b1, a, 0, 0, 0);
        acc[nb] = a;
        bv4[nb] = bias[cc0 + 16 * nb + llow];
    }

    const int bh = b * HH + h;
    if (mat == 0) {                                  // Q: pre-scale by 1/ln2
#pragma unroll
        for (int nb = 0; nb < 4; nb++)
#pragma unroll
            for (int r = 0; r < 4; r++) {
                const int s = s0 + 16 * wave + quad * 4 + r;
                Q16[((size_t)bh * SS + s) * 64 + 16 * nb + llow] =
                    (_Float16)((acc[nb][r] + bv4[nb]) * 1.4426950408889634f);
            }
    } else if (mat == 1) {
#pragma unroll
        for (int nb = 0; nb < 4; nb++)
#pragma unroll
            for (int r = 0; r < 4; r++) {
                const int s = s0 + 16 * wave + quad * 4 + r;
                K16[((size_t)bh * SS + s) * 64 + 16 * nb + llow] =
                    (_Float16)(acc[nb][r] + bv4[nb]);
            }
    } else {                                         // V^T bf16, tile-blocked
        const int tile = s0 >> 6;                    // block-uniform
        const int kin  = 16 * wave + quad * 4;       // in-tile key, 4 consecutive
#pragma unroll
        for (int nb = 0; nb < 4; nb++) {
            const int d = 16 * nb + llow;
            unsigned short p0 = f2bf(acc[nb][0] + bv4[nb]);
            unsigned short p1 = f2bf(acc[nb][1] + bv4[nb]);
            unsigned short p2 = f2bf(acc[nb][2] + bv4[nb]);
            unsigned short p3 = f2bf(acc[nb][3] + bv4[nb]);
            v2u pk = (v2u){(unsigned)p0 | ((unsigned)p1 << 16),
                           (unsigned)p2 | ((unsigned)p3 << 16)};
            *(v2u*)&VT[(((size_t)bh * 32 + tile) * 64 + d) * 64 + kin] = pk;
        }
    }
}

// ---------------------------------------------------------------------------
// Kernel 2: MFMA flash attention, R23 = hybrid transport. Pipe-isolation
// matrix across R15/R19/R20/R21 (all ~43-45us) points at the shared per-CU
// LDS pipe: DMA-write 16KB + 32 b128 K-reads + 64 b64 V-reads + conflicts
// ~= 1150 cy/tile-unit x 49.5 units/CU ~= 24us — the one resource all
// resident blocks contend on. R16/R22 showed V-direct fails only via
// strided layout / no prefetch / K redundancy. Hybrid: K keeps the R21
// pipeline (triple-buffer LDS, counted vmcnt, raw s_barrier, 2-ahead DMA);
// V is read per-wave DIRECT from tile-blocked VT2 (8KB, L1-resident across
// the 4 waves) into named double-buffered registers, issued ONE ROUND
// AHEAD (compiler-tracked waits). vmcnt counts: per round issue V(t+1)
// [16 loads] then K(t+2) [2 DMA]; at round top vmcnt(2) retires V(t) and
// K(t+1), leaving only K(t+2) in flight; final round vmcnt(0).
// LDS 24KB; expected LDS-pipe ~450cy/unit (-60%); V b64 conflicts gone.
// ---------------------------------------------------------------------------
struct VFrag { v4s v[16]; };   // V^T B-frags (K=16): [nb*4+cb]

__global__ __launch_bounds__(256, 4) void attn_kernel(
    const _Float16* __restrict__ Q16, const _Float16* __restrict__ K16,
    const unsigned short* __restrict__ VTg, _Float16* __restrict__ O16)
{
    __shared__ __align__(16) _Float16 Kl[3][64 * 64];   // [key][d], xor-swizzled

    const int bh    = blockIdx.y;
    const int qtile = (int)((blockIdx.x + 11 * blockIdx.y) & 31);   // balance swizzle
    const int wave  = threadIdx.x >> 6;
    const int lane  = threadIdx.x & 63;
    const int llow  = lane & 15;
    const int quad  = lane >> 4;
    const int q0    = qtile * 64 + 16 * wave;
    const int sw    = llow & 7;

    const _Float16*       Kp  = K16 + (size_t)bh * SS * 64;
    const unsigned short* Vp2 = VTg + (size_t)bh * 32 * 4096;

    const _Float16* Qp = Q16 + ((size_t)bh * SS + q0) * 64;
    v8h qa0 = *(const v8h*)(Qp + llow * 64 + quad * 8);
    v8h qa1 = *(const v8h*)(Qp + llow * 64 + 32 + quad * 8);

    v4f o[4];
    v4f ls = (v4f){0.f, 0.f, 0.f, 0.f};             // row sums via MFMA
    const short one_bf = (short)0x3F80;              // bf16 1.0
    const v4s vones = (v4s){one_bf, one_bf, one_bf, one_bf};
#pragma unroll
    for (int nb = 0; nb < 4; nb++) o[nb] = (v4f){0.f, 0.f, 0.f, 0.f};

    const int nt   = qtile + 1;     // 64-key tiles needed
    const int qrow = q0 + llow;

    // stage one 64-key K tile into buf b: 2 wave-level global_load_lds
    auto stageK = [&](int kt, int b) {
#pragma unroll
        for (int rep = 0; rep < 2; rep++) {
            int c = rep * 256 + threadIdx.x;
            int row = c >> 3, g = (c & 7) ^ (row & 7);
            async16(Kp + (size_t)(kt + row) * 64 + g * 8,
                    &Kl[b][(rep * 256 + wave * 64) * 8]);
        }
    };

    // load tile t's V^T fragments direct to regs (8KB L1-resident tile)
    auto loadV = [&](VFrag& f, int t) {
        const unsigned short* vb = Vp2 + (size_t)t * 4096;
#pragma unroll
        for (int nb = 0; nb < 4; nb++)
#pragma unroll
            for (int cb = 0; cb < 4; cb++)
                f.v[nb * 4 + cb] = *(const v4s*)(vb + (16 * nb + llow) * 64
                                                 + 16 * cb + 4 * quad);
    };

    auto round_body = [&](int t, VFrag& cur, VFrag& nxt, auto masked_c) {
        constexpr bool MASKED = decltype(masked_c)::value;
        if constexpr (MASKED)
            asm volatile("s_waitcnt vmcnt(0)" ::: "memory");
        else
            asm volatile("s_waitcnt vmcnt(2)" ::: "memory");  // only K(t+2) DMA may remain
        __builtin_amdgcn_s_barrier();                          // raw: no auto-drain
        __builtin_amdgcn_sched_barrier(0);                     // pin ds_reads below
        if (t + 1 < nt) loadV(nxt, t + 1);                     // reg prefetch, 1 ahead
        if (t + 2 < nt) stageK((t + 2) * 64, (t + 2) % 3);     // DMA prefetch, 2 ahead
        const int buf = t % 3, kt = t * 64;

        // ---- S^T = K·Q^T over all 64 keys: 4 col-blocks of 16 ----
        v4f sc[4];
#pragma unroll
        for (int cb = 0; cb < 4; cb++) {
            const int rk = 16 * cb + llow;                       // rk&7 == sw
            v8h k0 = *(const v8h*)&Kl[buf][rk * 64 + ((quad ^ sw)) * 8];
            v8h k1 = *(const v8h*)&Kl[buf][rk * 64 + (((4 + quad) ^ sw)) * 8];
            v4f a2 = (v4f){0.f, 0.f, 0.f, 0.f};
            a2 = __builtin_amdgcn_mfma_f32_16x16x32_f16(k0, qa0, a2, 0, 0, 0);
            a2 = __builtin_amdgcn_mfma_f32_16x16x32_f16(k1, qa1, a2, 0, 0, 0);
            sc[cb] = a2;  // C: col=llow=q-row, row=quad*4+r=key offset
        }

        // ---- quirky mask + exp2; pack P pairs in-register (K=16 A-frags) ----
        v4s pA[4];
#pragma unroll
        for (int cb = 0; cb < 4; cb++) {
            const int kbase = kt + 16 * cb + quad * 4;
            unsigned dw[2];
#pragma unroll
            for (int h2 = 0; h2 < 2; h2++) {
                float pv2[2];
#pragma unroll
                for (int j2 = 0; j2 < 2; j2++) {
                    const int r = h2 * 2 + j2;
                    const float sv = sc[cb][r];
                    const float e  = __builtin_amdgcn_exp2f(sv - C2FIX);
                    float p;
                    if constexpr (MASKED)
                        p = (kbase + r <= qrow && sv != 0.f) ? e : 0.f;
                    else
                        p = (sv != 0.f) ? e : 0.f;   // tril-zero quirk only
                    pv2[j2] = p;
                }
                dw[h2] = __builtin_amdgcn_perm(__float_as_uint(pv2[1]),
                                               __float_as_uint(pv2[0]),
                                               0x07060302u);
            }
            v2u pk = (v2u){dw[0], dw[1]};
            pA[cb] = *(const v4s*)&pk;   // A[row=llow][k=4quad+j]
        }

        // ---- row sums on the MFMA pipe: ls += P · ones (K=16) ----
#pragma unroll
        for (int cb = 0; cb < 4; cb++)
            ls = __builtin_amdgcn_mfma_f32_16x16x16bf16_1k(pA[cb], vones, ls, 0, 0, 0);

        // ---- PV via K=16 MFMAs (V frags in regs) ----
#pragma unroll
        for (int nb = 0; nb < 4; nb++)
#pragma unroll
            for (int cb = 0; cb < 4; cb++)
                o[nb] = __builtin_amdgcn_mfma_f32_16x16x16bf16_1k(
                            pA[cb], cur.v[nb * 4 + cb], o[nb], 0, 0, 0);
    };

    // prologue: V(0) to regs; K tiles 0,1 to LDS (issue order: V first!)
    VFrag vA, vB;
    loadV(vA, 0);
    stageK(0, 0);
    if (nt > 1) stageK(64, 1);

    int t = 0;
    while (t + 2 <= nt - 1) {            // t and t+1 both non-final
        round_body(t,     vA, vB, std::false_type{});
        round_body(t + 1, vB, vA, std::false_type{});
        t += 2;
    }
    if (t == nt - 2) {                   // t non-final, t+1 final
        round_body(t,     vA, vB, std::false_type{});
        round_body(t + 1, vB, vA, std::true_type{});
    } else {                             // t == nt-1: final tile, V in vA
        round_body(t,     vA, vB, std::true_type{});
    }

    // ---- epilogue: ls[r] IS the full row sum for row quad*4+r ----
    float ir[4];
#pragma unroll
    for (int r = 0; r < 4; r++)
        ir[r] = 1.0f / ls[r];
    _Float16* Op = O16 + ((size_t)bh * SS + q0) * 64;
#pragma unroll
    for (int nb = 0; nb < 4; nb++)
#pragma unroll
        for (int r = 0; r < 4; r++)
            Op[(quad * 4 + r) * 64 + 16 * nb + llow] = (_Float16)(o[nb][r] * ir[r]);
}

// ---------------------------------------------------------------------------
// Kernel 3: output projection via MFMA (unchanged).
// ---------------------------------------------------------------------------
__global__ __launch_bounds__(256) void out_kernel(
    const _Float16* __restrict__ O16, const _Float16* __restrict__ WoT,
    const float* __restrict__ bo, float* __restrict__ out)
{
    __shared__ __align__(16) float red[4][16][66];
    const int r0   = blockIdx.x * 16;
    const int wave = threadIdx.x >> 6, lane = threadIdx.x & 63;
    const int llow = lane & 15, quad = lane >> 4;
    const int b = r0 >> 11, s = r0 & 2047;

    v4f acc[4];
#pragma unroll
    for (int cb = 0; cb < 4; cb++) acc[cb] = (v4f){0.f, 0.f, 0.f, 0.f};

#pragma unroll
    for (int i = 0; i < 6; i++) {
        const int kb = wave * 6 + i;                // 0..23
        const int h = kb >> 1, dseg = (kb & 1) * 32;
        v8h af = *(const v8h*)(O16 + ((size_t)(b * HH + h) * SS + s + llow) * 64 + dseg + quad * 8);
#pragma unroll
        for (int cb = 0; cb < 4; cb++) {
            v8h bf = *(const v8h*)(WoT + (size_t)(16 * cb + llow) * 768 + kb * 32 + quad * 8);
            acc[cb] = __builtin_amdgcn_mfma_f32_16x16x32_f16(af, bf, acc[cb], 0, 0, 0);
        }
    }

#pragma unroll
    for (int cb = 0; cb < 4; cb++)
#pragma unroll
        for (int r = 0; r < 4; r++)
            red[wave][quad * 4 + r][16 * cb + llow] = acc[cb][r];
    __syncthreads();

    const int col = threadIdx.x & 63, rr = threadIdx.x >> 6;
    const float bias = bo[col];
    for (int i = rr; i < 16; i += 4) {
        float sum = red[0][i][col] + red[1][i][col] + red[2][i][col] + red[3][i][col] + bias;
        out[(size_t)(r0 + i) * 64 + col] = sum;
    }
}

// ---------------------------------------------------------------------------
extern "C" void kernel_launch(void* const* d_in, const int* in_sizes, int n_in,
                              void* d_out, int out_size, void* d_ws, size_t ws_size,
                              hipStream_t stream)
{
    const float* x  = (const float*)d_in[0];
    const float* Wq = (const float*)d_in[1];
    const float* bq = (const float*)d_in[2];
    const float* Wk = (const float*)d_in[3];
    const float* bk = (const float*)d_in[4];
    const float* Wv = (const float*)d_in[5];
    const float* bv = (const float*)d_in[6];
    const float* Wo = (const float*)d_in[7];
    const float* bo = (const float*)d_in[8];
    float* out = (float*)d_out;

    char* w = (char*)d_ws;
    const size_t MB = 1024 * 1024;
    _Float16*       x16 = (_Float16*)(w);                 // 512 KB
    _Float16*       W16 = (_Float16*)(w + 512 * 1024);    // 288 KB
    _Float16*       WoT = (_Float16*)(w + 832 * 1024);    // 96 KB
    _Float16*       Q16 = (_Float16*)(w + 1 * MB);        // 6 MB each
    _Float16*       K16 = (_Float16*)(w + 7 * MB);
    unsigned short* VT  = (unsigned short*)(w + 13 * MB);
    _Float16*       O16 = (_Float16*)(w + 19 * MB);

    prep_kernel<<<1792, 256, 0, stream>>>(x, Wq, Wk, Wv, Wo, x16, W16, WoT);
    qkv_kernel<<<dim3(64, 36), 256, 0, stream>>>(x16, W16, bq, bk, bv, Q16, K16, VT);
    attn_kernel<<<dim3(32, BB * HH), 256, 0, stream>>>(Q16, K16, VT, O16);
    out_kernel<<<(BB * SS) / 16, 256, 0, stream>>>(O16, WoT, bo, out);
}